// Round 1
// baseline (1509.623 us; speedup 1.0000x reference)
//
#include <hip/hip_runtime.h>
#include <math.h>

#define NN 100000
#define NE 1600000
#define INF_ 128
#define HID 64
#define NEG 0.2f

__device__ __forceinline__ float lrelu(float v){ return v > 0.f ? v : NEG*v; }

// order-preserving float<->uint encoding for atomicMax on floats
__device__ __forceinline__ unsigned fenc(float f){
  unsigned u = __float_as_uint(f);
  return (u & 0x80000000u) ? ~u : (u | 0x80000000u);
}
__device__ __forceinline__ float fdec(unsigned u){
  return (u & 0x80000000u) ? __uint_as_float(u & 0x7fffffffu) : __uint_as_float(~u);
}

__global__ void k_zero(float* p, int n){
  int i = blockIdx.x*blockDim.x + threadIdx.x;
  if (i < n) p[i] = 0.f;
}

// count incoming edges per dst (raw edges; GCN deg = cnt+1, SAGE divisor = max(cnt,1))
__global__ void k_count(const int* __restrict__ dst, float* __restrict__ cnt){
  int e = blockIdx.x*blockDim.x + threadIdx.x;
  if (e < NE) atomicAdd(&cnt[dst[e]], 1.0f);
}

__global__ void k_dinv(const float* __restrict__ cnt, float* __restrict__ dinv){
  int i = blockIdx.x*blockDim.x + threadIdx.x;
  if (i < NN) dinv[i] = rsqrtf(cnt[i] + 1.0f);
}

// h[N,64] = x[N,128] @ w[128,64]   (row per wave, W staged in LDS)
__global__ __launch_bounds__(256) void k_gemm_in(const float* __restrict__ x,
                                                 const float* __restrict__ w,
                                                 float* __restrict__ out){
  __shared__ float wl[INF_*HID];
  __shared__ float xl[4][INF_];
  for (int i = threadIdx.x; i < INF_*HID; i += 256) wl[i] = w[i];
  __syncthreads();
  const int wave = threadIdx.x >> 6, lane = threadIdx.x & 63;
  for (int row = blockIdx.x*4 + wave; row < NN; row += gridDim.x*4){
    xl[wave][lane]      = x[row*INF_ + lane];
    xl[wave][lane + 64] = x[row*INF_ + lane + 64];
    float acc = 0.f;
    #pragma unroll
    for (int k = 0; k < INF_; ++k) acc += xl[wave][k]*wl[k*HID + lane];
    out[row*HID + lane] = acc;
  }
}

// agg[i] = h[i] * dinv[i]^2   (GCN self-loop term, also initializes agg)
__global__ void k_gcn_self(const float* __restrict__ h, const float* __restrict__ dinv,
                           float* __restrict__ agg){
  int i = blockIdx.x*blockDim.x + threadIdx.x;
  if (i < NN*HID){
    int r = i >> 6;
    float d = dinv[r];
    agg[i] = h[i]*d*d;
  }
}

// one wave per edge: agg[dst] += h[src]*dinv[src]*dinv[dst]
__global__ __launch_bounds__(256) void k_gcn_edge(const int* __restrict__ src,
                                                  const int* __restrict__ dst,
                                                  const float* __restrict__ h,
                                                  const float* __restrict__ dinv,
                                                  float* agg){
  int e = blockIdx.x*4 + (threadIdx.x >> 6);
  if (e >= NE) return;
  int lane = threadIdx.x & 63;
  int s = src[e], d = dst[e];
  float nrm = dinv[s]*dinv[d];
  atomicAdd(&agg[d*HID + lane], h[s*HID + lane]*nrm);
}

// h1 = relu(agg + gcn_b); h2pre = h1 @ gat_w; a_s = h2pre.att_src; a_d = h2pre.att_dst
__global__ __launch_bounds__(256) void k_gat_lin(const float* __restrict__ agg,
                                                 const float* __restrict__ gcn_b,
                                                 const float* __restrict__ w,
                                                 const float* __restrict__ atts,
                                                 const float* __restrict__ attd,
                                                 float* __restrict__ h2pre,
                                                 float* __restrict__ as_,
                                                 float* __restrict__ ad_){
  __shared__ float wl[HID*HID];
  __shared__ float bl[HID], asl[HID], adl[HID];
  __shared__ float hl[4][HID];
  for (int i = threadIdx.x; i < HID*HID; i += 256) wl[i] = w[i];
  if (threadIdx.x < HID){
    bl[threadIdx.x]  = gcn_b[threadIdx.x];
    asl[threadIdx.x] = atts[threadIdx.x];
    adl[threadIdx.x] = attd[threadIdx.x];
  }
  __syncthreads();
  const int wave = threadIdx.x >> 6, lane = threadIdx.x & 63;
  for (int row = blockIdx.x*4 + wave; row < NN; row += gridDim.x*4){
    float h1 = fmaxf(agg[row*HID + lane] + bl[lane], 0.f);
    hl[wave][lane] = h1;
    float acc = 0.f;
    #pragma unroll
    for (int k = 0; k < HID; ++k) acc += hl[wave][k]*wl[k*HID + lane];
    h2pre[row*HID + lane] = acc;
    float vs = acc*asl[lane], vd = acc*adl[lane];
    #pragma unroll
    for (int o = 32; o > 0; o >>= 1){
      vs += __shfl_xor(vs, o, 64);
      vd += __shfl_xor(vd, o, 64);
    }
    if (lane == 0){ as_[row] = vs; ad_[row] = vd; }
  }
}

// m init with self-loop edge value (encoded)
__global__ void k_gat_init(const float* __restrict__ as_, const float* __restrict__ ad_,
                           unsigned* __restrict__ menc){
  int i = blockIdx.x*blockDim.x + threadIdx.x;
  if (i < NN) menc[i] = fenc(lrelu(as_[i] + ad_[i]));
}

__global__ void k_gat_max(const int* __restrict__ src, const int* __restrict__ dst,
                          const float* __restrict__ as_, const float* __restrict__ ad_,
                          unsigned* menc){
  int e = blockIdx.x*blockDim.x + threadIdx.x;
  if (e < NE){
    float ev = lrelu(as_[src[e]] + ad_[dst[e]]);
    atomicMax(&menc[dst[e]], fenc(ev));
  }
}

// decode m to float (in place), ssum = p_self, agg = h2pre * p_self
__global__ __launch_bounds__(256) void k_gat_init2(const float* __restrict__ as_,
                                                   const float* __restrict__ ad_,
                                                   unsigned* menc_io,
                                                   float* __restrict__ ssum,
                                                   const float* __restrict__ h2pre,
                                                   float* __restrict__ agg){
  int i = blockIdx.x*4 + (threadIdx.x >> 6);
  if (i >= NN) return;
  int lane = threadIdx.x & 63;
  float m = fdec(menc_io[i]);                 // all lanes read before lane0 overwrites
  float ps = expf(lrelu(as_[i] + ad_[i]) - m);
  if (lane == 0){ ((float*)menc_io)[i] = m; ssum[i] = ps; }
  agg[i*HID + lane] = h2pre[i*HID + lane]*ps;
}

// one wave per edge: p = exp(e - m[dst]); s[dst] += p; agg[dst] += p*h2pre[src]
__global__ __launch_bounds__(256) void k_gat_edge(const int* __restrict__ src,
                                                  const int* __restrict__ dst,
                                                  const float* __restrict__ as_,
                                                  const float* __restrict__ ad_,
                                                  const float* __restrict__ m,
                                                  const float* __restrict__ h2pre,
                                                  float* ssum, float* agg){
  int e = blockIdx.x*4 + (threadIdx.x >> 6);
  if (e >= NE) return;
  int lane = threadIdx.x & 63;
  int s = src[e], d = dst[e];
  float p = expf(lrelu(as_[s] + ad_[d]) - m[d]);
  if (lane == 0) atomicAdd(&ssum[d], p);
  atomicAdd(&agg[d*HID + lane], p*h2pre[s*HID + lane]);
}

// h2 = relu(agg/s + gat_b)
__global__ void k_gat_fin(const float* __restrict__ agg, const float* __restrict__ ssum,
                          const float* __restrict__ gat_b, float* __restrict__ h2out){
  int i = blockIdx.x*blockDim.x + threadIdx.x;
  if (i < NN*HID){
    int r = i >> 6, c = i & 63;
    h2out[i] = fmaxf(agg[i]/ssum[r] + gat_b[c], 0.f);
  }
}

// one wave per edge: ssum[dst] += h2[src]
__global__ __launch_bounds__(256) void k_sage_edge(const int* __restrict__ src,
                                                   const int* __restrict__ dst,
                                                   const float* __restrict__ h2,
                                                   float* ssum){
  int e = blockIdx.x*4 + (threadIdx.x >> 6);
  if (e >= NE) return;
  int lane = threadIdx.x & 63;
  atomicAdd(&ssum[dst[e]*HID + lane], h2[src[e]*HID + lane]);
}

// out = (ssum/max(cnt,1)) @ wl + h2 @ wr + b
// NOTE: no __restrict__ on h2/out — they may alias (d_out reuse in small-ws path);
// per-row read->LDS->compute->write order makes that safe.
__global__ __launch_bounds__(256) void k_sage_fin(const float* __restrict__ ssum,
                                                  const float* __restrict__ cnt,
                                                  const float* h2,
                                                  const float* __restrict__ wlh,
                                                  const float* __restrict__ wrh,
                                                  const float* __restrict__ b,
                                                  float* out){
  __shared__ float wll[HID*HID], wrl[HID*HID], bl[HID];
  __shared__ float ml[4][HID], hl[4][HID];
  for (int i = threadIdx.x; i < HID*HID; i += 256){ wll[i] = wlh[i]; wrl[i] = wrh[i]; }
  if (threadIdx.x < HID) bl[threadIdx.x] = b[threadIdx.x];
  __syncthreads();
  const int wave = threadIdx.x >> 6, lane = threadIdx.x & 63;
  for (int row = blockIdx.x*4 + wave; row < NN; row += gridDim.x*4){
    float inv = 1.f/fmaxf(cnt[row], 1.f);
    ml[wave][lane] = ssum[row*HID + lane]*inv;
    hl[wave][lane] = h2[row*HID + lane];
    float acc = bl[lane];
    #pragma unroll
    for (int k = 0; k < HID; ++k)
      acc += ml[wave][k]*wll[k*HID + lane] + hl[wave][k]*wrl[k*HID + lane];
    out[row*HID + lane] = acc;
  }
}

extern "C" void kernel_launch(void* const* d_in, const int* in_sizes, int n_in,
                              void* d_out, int out_size, void* d_ws, size_t ws_size,
                              hipStream_t stream) {
  const float* x      = (const float*)d_in[0];
  const int*   ei     = (const int*)d_in[1];
  const int*   src    = ei;
  const int*   dstp   = ei + NE;
  const float* gcn_w  = (const float*)d_in[2];
  const float* gcn_b  = (const float*)d_in[3];
  const float* gat_w  = (const float*)d_in[4];
  const float* att_s  = (const float*)d_in[5];
  const float* att_d  = (const float*)d_in[6];
  const float* gat_b  = (const float*)d_in[7];
  const float* s_wl   = (const float*)d_in[8];
  const float* s_wr   = (const float*)d_in[9];
  const float* s_b    = (const float*)d_in[10];
  float* outp = (float*)d_out;

  float* ws   = (float*)d_ws;
  float* cnt  = ws;              // N
  float* dinv = cnt  + NN;       // N
  float* as_  = dinv + NN;       // N
  float* ad_  = as_  + NN;       // N
  float* mbuf = ad_  + NN;       // N (uint encoded max, then float m)
  float* ssum = mbuf + NN;       // N
  float* B1   = ssum + NN;       // N*HID (agg_gcn -> agg_gat -> sage ssum)

  // big-buffer assignments; prefer a second ws buffer, fall back to d_out reuse
  size_t need2 = (size_t)(6*NN + 2*NN*HID) * 4;
  float *Bh, *Bh2;               // h (GCN linear out), h2 (GAT output)
  float* h2pre = outp;           // GAT linear output lives in d_out (dead before final write)
  if (ws_size >= need2){
    Bh  = B1 + NN*HID;           // second big ws buffer
    Bh2 = Bh;                    // h dead before h2 written -> reuse
  } else {
    Bh  = outp;                  // 1-buffer fallback: h and h2 live in d_out
    Bh2 = outp;                  //  (h2pre is also outp; sequencing keeps them disjoint in time)
  }

  const int B = 256;
  // degree count (shared by GCN and SAGE)
  k_zero <<<(NN + B-1)/B, B, 0, stream>>>(cnt, NN);
  k_count<<<(NE + B-1)/B, B, 0, stream>>>(dstp, cnt);
  k_dinv <<<(NN + B-1)/B, B, 0, stream>>>(cnt, dinv);

  // GCN
  k_gemm_in <<<2048, B, 0, stream>>>(x, gcn_w, Bh);
  k_gcn_self<<<(NN*HID + B-1)/B, B, 0, stream>>>(Bh, dinv, B1);
  k_gcn_edge<<<(NE + 3)/4, B, 0, stream>>>(src, dstp, Bh, dinv, B1);

  // GAT linear (+GCN bias/relu fused)
  k_gat_lin <<<2048, B, 0, stream>>>(B1, gcn_b, gat_w, att_s, att_d, h2pre, as_, ad_);
  k_gat_init<<<(NN + B-1)/B, B, 0, stream>>>(as_, ad_, (unsigned*)mbuf);
  k_gat_max <<<(NE + B-1)/B, B, 0, stream>>>(src, dstp, as_, ad_, (unsigned*)mbuf);
  k_gat_init2<<<(NN + 3)/4, B, 0, stream>>>(as_, ad_, (unsigned*)mbuf, ssum, h2pre, B1);
  k_gat_edge<<<(NE + 3)/4, B, 0, stream>>>(src, dstp, as_, ad_, mbuf, h2pre, ssum, B1);
  k_gat_fin <<<(NN*HID + B-1)/B, B, 0, stream>>>(B1, ssum, gat_b, Bh2);

  // SAGE
  k_zero     <<<(NN*HID + B-1)/B, B, 0, stream>>>(B1, NN*HID);
  k_sage_edge<<<(NE + 3)/4, B, 0, stream>>>(src, dstp, Bh2, B1);
  k_sage_fin <<<2048, B, 0, stream>>>(B1, cnt, Bh2, s_wl, s_wr, s_b, outp);
}

// Round 2
// 693.747 us; speedup vs baseline: 2.1760x; 2.1760x over previous
//
#include <hip/hip_runtime.h>
#include <math.h>

#define NN 100000
#define NE 1600000
#define INF_ 128
#define HID 64
#define NEG 0.2f
#define NBLK1 98   // ceil(NN/1024) for scan

__device__ __forceinline__ float lrelu(float v){ return v > 0.f ? v : NEG*v; }

// ---------------- CSR build ----------------

__global__ void k_zero_i(int* p, int n){
  int i = blockIdx.x*blockDim.x + threadIdx.x;
  if (i < n) p[i] = 0;
}

__global__ void k_count(const int* __restrict__ dst, int* __restrict__ cnt){
  int e = blockIdx.x*blockDim.x + threadIdx.x;
  if (e < NE) atomicAdd(&cnt[dst[e]], 1);
}

// block-level scan: 256 threads x 4 elements; exclusive offsets + block partial
__global__ __launch_bounds__(256) void k_scan1(const int* __restrict__ cnt,
                                               int* __restrict__ off,
                                               int* __restrict__ part){
  __shared__ int l[256];
  int t = threadIdx.x;
  int base = blockIdx.x*1024 + t*4;
  int a0 = (base+0 < NN) ? cnt[base+0] : 0;
  int a1 = (base+1 < NN) ? cnt[base+1] : 0;
  int a2 = (base+2 < NN) ? cnt[base+2] : 0;
  int a3 = (base+3 < NN) ? cnt[base+3] : 0;
  int s = a0+a1+a2+a3;
  l[t] = s; __syncthreads();
  for (int o = 1; o < 256; o <<= 1){
    int v = (t >= o) ? l[t-o] : 0;
    __syncthreads();
    l[t] += v;
    __syncthreads();
  }
  if (t == 255) part[blockIdx.x] = l[255];
  int e0 = l[t] - s;   // exclusive within block
  if (base+0 < NN) off[base+0] = e0;
  if (base+1 < NN) off[base+1] = e0 + a0;
  if (base+2 < NN) off[base+2] = e0 + a0 + a1;
  if (base+3 < NN) off[base+3] = e0 + a0 + a1 + a2;
}

__global__ __launch_bounds__(128) void k_scan2(int* part){
  __shared__ int l[128];
  int t = threadIdx.x;
  int v = (t < NBLK1) ? part[t] : 0;
  l[t] = v; __syncthreads();
  for (int o = 1; o < 128; o <<= 1){
    int u = (t >= o) ? l[t-o] : 0;
    __syncthreads();
    l[t] += u;
    __syncthreads();
  }
  if (t < NBLK1) part[t] = l[t] - v;   // exclusive block offsets
}

__global__ void k_scan3(int* off, const int* __restrict__ part){
  int i = blockIdx.x*blockDim.x + threadIdx.x;
  if (i < NN) off[i] += part[i >> 10];
  if (i == 0) off[NN] = NE;
}

__global__ void k_fill(const int* __restrict__ src, const int* __restrict__ dst,
                       const int* __restrict__ off, int* cur, int* __restrict__ csr){
  int e = blockIdx.x*blockDim.x + threadIdx.x;
  if (e < NE){
    int d = dst[e];
    int p = atomicAdd(&cur[d], 1);
    csr[off[d] + p] = src[e];
  }
}

__global__ void k_dinv(const int* __restrict__ cnt, float* __restrict__ dinv){
  int i = blockIdx.x*blockDim.x + threadIdx.x;
  if (i < NN) dinv[i] = rsqrtf((float)cnt[i] + 1.0f);
}

// ---------------- dense linears ----------------

// h[N,64] = x[N,128] @ w[128,64]   (row per wave, W staged in LDS)
__global__ __launch_bounds__(256) void k_gemm_in(const float* __restrict__ x,
                                                 const float* __restrict__ w,
                                                 float* __restrict__ out){
  __shared__ float wl[INF_*HID];
  __shared__ float xl[4][INF_];
  for (int i = threadIdx.x; i < INF_*HID; i += 256) wl[i] = w[i];
  __syncthreads();
  const int wave = threadIdx.x >> 6, lane = threadIdx.x & 63;
  for (int row = blockIdx.x*4 + wave; row < NN; row += gridDim.x*4){
    xl[wave][lane]      = x[row*INF_ + lane];
    xl[wave][lane + 64] = x[row*INF_ + lane + 64];
    float acc = 0.f;
    #pragma unroll
    for (int k = 0; k < INF_; ++k) acc += xl[wave][k]*wl[k*HID + lane];
    out[row*HID + lane] = acc;
  }
}

// h2pre = h1 @ gat_w; as_ = h2pre.att_src; ad_ = h2pre.att_dst  (h1 already bias+relu'd)
__global__ __launch_bounds__(256) void k_gat_lin(const float* __restrict__ h1,
                                                 const float* __restrict__ w,
                                                 const float* __restrict__ atts,
                                                 const float* __restrict__ attd,
                                                 float* __restrict__ h2pre,
                                                 float* __restrict__ as_,
                                                 float* __restrict__ ad_){
  __shared__ float wl[HID*HID];
  __shared__ float asl[HID], adl[HID];
  __shared__ float hl[4][HID];
  for (int i = threadIdx.x; i < HID*HID; i += 256) wl[i] = w[i];
  if (threadIdx.x < HID){
    asl[threadIdx.x] = atts[threadIdx.x];
    adl[threadIdx.x] = attd[threadIdx.x];
  }
  __syncthreads();
  const int wave = threadIdx.x >> 6, lane = threadIdx.x & 63;
  for (int row = blockIdx.x*4 + wave; row < NN; row += gridDim.x*4){
    hl[wave][lane] = h1[row*HID + lane];
    float acc = 0.f;
    #pragma unroll
    for (int k = 0; k < HID; ++k) acc += hl[wave][k]*wl[k*HID + lane];
    h2pre[row*HID + lane] = acc;
    float vs = acc*asl[lane], vd = acc*adl[lane];
    #pragma unroll
    for (int o = 32; o > 0; o >>= 1){
      vs += __shfl_xor(vs, o, 64);
      vd += __shfl_xor(vd, o, 64);
    }
    if (lane == 0){ as_[row] = vs; ad_[row] = vd; }
  }
}

// ---------------- gather aggregations (no atomics) ----------------

// GCN: h1 = relu((h[i]*dinv[i] + sum_s h[s]*dinv[s]) * dinv[i] + gcn_b)
__global__ __launch_bounds__(256) void k_gcn_gather(const int* __restrict__ csr,
                                                    const int* __restrict__ off,
                                                    const float* __restrict__ h,
                                                    const float* __restrict__ dinv,
                                                    const float* __restrict__ gcn_b,
                                                    float* __restrict__ h1){
  int node = blockIdx.x*4 + (threadIdx.x >> 6);
  if (node >= NN) return;
  int lane = threadIdx.x & 63;
  int beg = off[node], end = off[node+1];
  float di = dinv[node];
  float acc = h[node*HID + lane]*di;
  for (int c = beg; c < end; c += 64){
    int n = end - c; if (n > 64) n = 64;
    int idx = 0; float dv = 0.f;
    if (lane < n){ idx = csr[c + lane]; dv = dinv[idx]; }
    int k = 0;
    for (; k + 1 < n; k += 2){
      int s0 = __shfl(idx, k, 64);   float w0 = __shfl(dv, k, 64);
      int s1 = __shfl(idx, k+1, 64); float w1 = __shfl(dv, k+1, 64);
      float r0 = h[s0*HID + lane];
      float r1 = h[s1*HID + lane];
      acc += r0*w0;
      acc += r1*w1;
    }
    if (k < n){
      int s0 = __shfl(idx, k, 64); float w0 = __shfl(dv, k, 64);
      acc += h[s0*HID + lane]*w0;
    }
  }
  h1[node*HID + lane] = fmaxf(acc*di + gcn_b[lane], 0.f);
}

// GAT: register-resident segment softmax + weighted gather, fully fused
__global__ __launch_bounds__(256) void k_gat_gather(const int* __restrict__ csr,
                                                    const int* __restrict__ off,
                                                    const float* __restrict__ as_,
                                                    const float* __restrict__ ad_,
                                                    const float* __restrict__ h2pre,
                                                    const float* __restrict__ gat_b,
                                                    float* __restrict__ h2){
  int node = blockIdx.x*4 + (threadIdx.x >> 6);
  if (node >= NN) return;
  int lane = threadIdx.x & 63;
  int beg = off[node], end = off[node+1];
  float adi = ad_[node];
  float eself = lrelu(as_[node] + adi);
  // pass 1: max over incoming edges (lane-parallel)
  float lm = -1e30f;
  for (int c = beg + lane; c < end; c += 64)
    lm = fmaxf(lm, lrelu(as_[csr[c]] + adi));
  #pragma unroll
  for (int o = 32; o > 0; o >>= 1) lm = fmaxf(lm, __shfl_xor(lm, o, 64));
  float m = fmaxf(eself, lm);
  // pass 2: p-sum and weighted row accumulation
  float ssum = expf(eself - m);            // self-loop p
  float acc = h2pre[node*HID + lane]*ssum;
  for (int c = beg; c < end; c += 64){
    int n = end - c; if (n > 64) n = 64;
    int idx = 0; float pv = 0.f;
    if (lane < n){
      idx = csr[c + lane];
      pv = expf(lrelu(as_[idx] + adi) - m);
    }
    int k = 0;
    for (; k + 1 < n; k += 2){
      int s0 = __shfl(idx, k, 64);   float p0 = __shfl(pv, k, 64);
      int s1 = __shfl(idx, k+1, 64); float p1 = __shfl(pv, k+1, 64);
      float r0 = h2pre[s0*HID + lane];
      float r1 = h2pre[s1*HID + lane];
      ssum += p0 + p1;
      acc += r0*p0;
      acc += r1*p1;
    }
    if (k < n){
      int s0 = __shfl(idx, k, 64); float p0 = __shfl(pv, k, 64);
      ssum += p0;
      acc += h2pre[s0*HID + lane]*p0;
    }
  }
  h2[node*HID + lane] = fmaxf(acc/ssum + gat_b[lane], 0.f);
}

// SAGE: gather mean fused with final GEMM: out = mean@wl + h2@wr + b
__global__ __launch_bounds__(256) void k_sage_fin(const int* __restrict__ csr,
                                                  const int* __restrict__ off,
                                                  const int* __restrict__ cnt,
                                                  const float* __restrict__ h2,
                                                  const float* __restrict__ wlh,
                                                  const float* __restrict__ wrh,
                                                  const float* __restrict__ b,
                                                  float* __restrict__ out){
  __shared__ float wll[HID*HID], wrl[HID*HID], bl[HID];
  __shared__ float ml[4][HID], hl[4][HID];
  for (int i = threadIdx.x; i < HID*HID; i += 256){ wll[i] = wlh[i]; wrl[i] = wrh[i]; }
  if (threadIdx.x < HID) bl[threadIdx.x] = b[threadIdx.x];
  __syncthreads();
  const int wave = threadIdx.x >> 6, lane = threadIdx.x & 63;
  for (int node = blockIdx.x*4 + wave; node < NN; node += gridDim.x*4){
    int beg = off[node], end = off[node+1];
    float acc = 0.f;
    for (int c = beg; c < end; c += 64){
      int n = end - c; if (n > 64) n = 64;
      int idx = 0;
      if (lane < n) idx = csr[c + lane];
      int k = 0;
      for (; k + 1 < n; k += 2){
        int s0 = __shfl(idx, k, 64);
        int s1 = __shfl(idx, k+1, 64);
        float r0 = h2[s0*HID + lane];
        float r1 = h2[s1*HID + lane];
        acc += r0;
        acc += r1;
      }
      if (k < n) acc += h2[__shfl(idx, k, 64)*HID + lane];
    }
    float inv = 1.f/fmaxf((float)cnt[node], 1.f);
    ml[wave][lane] = acc*inv;
    hl[wave][lane] = h2[node*HID + lane];
    float o = bl[lane];
    #pragma unroll
    for (int kk = 0; kk < HID; ++kk)
      o += ml[wave][kk]*wll[kk*HID + lane] + hl[wave][kk]*wrl[kk*HID + lane];
    out[node*HID + lane] = o;
  }
}

// ---------------- launch ----------------

extern "C" void kernel_launch(void* const* d_in, const int* in_sizes, int n_in,
                              void* d_out, int out_size, void* d_ws, size_t ws_size,
                              hipStream_t stream) {
  const float* x      = (const float*)d_in[0];
  const int*   ei     = (const int*)d_in[1];
  const int*   src    = ei;
  const int*   dstp   = ei + NE;
  const float* gcn_w  = (const float*)d_in[2];
  const float* gcn_b  = (const float*)d_in[3];
  const float* gat_w  = (const float*)d_in[4];
  const float* att_s  = (const float*)d_in[5];
  const float* att_d  = (const float*)d_in[6];
  const float* gat_b  = (const float*)d_in[7];
  const float* s_wl   = (const float*)d_in[8];
  const float* s_wr   = (const float*)d_in[9];
  const float* s_b    = (const float*)d_in[10];
  float* outp = (float*)d_out;

  // workspace layout (4-byte words)
  int*   cnt  = (int*)d_ws;          // N
  int*   cur  = cnt + NN;            // N
  int*   off  = cur + NN;            // N+1
  int*   part = off + NN + 1;        // 1024 (pad)
  float* dinv = (float*)(part + 1024);
  float* as_  = dinv + NN;
  float* ad_  = as_  + NN;
  int*   csr  = (int*)(ad_ + NN);    // NE
  float* BIG0 = (float*)(csr + NE);  // N*HID
  float* BIG1 = BIG0 + (size_t)NN*HID;

  size_t need_full = ((size_t)5*NN + 1 + 1024 + NE + (size_t)2*NN*HID)*4;
  float *P_h, *P_h1, *P_h2pre, *P_h2;
  if (ws_size >= need_full){
    P_h = BIG0; P_h1 = BIG1; P_h2pre = outp; P_h2 = BIG1;   // h1 dead before h2 written
  } else {
    P_h = outp; P_h1 = BIG0; P_h2pre = outp; P_h2 = BIG0;   // d_out time-shared
  }

  const int B = 256;
  // CSR build (counting sort by dst)
  k_zero_i<<<(2*NN + B-1)/B, B, 0, stream>>>(cnt, 2*NN);     // cnt + cur contiguous
  k_count <<<(NE + B-1)/B, B, 0, stream>>>(dstp, cnt);
  k_scan1 <<<NBLK1, B, 0, stream>>>(cnt, off, part);
  k_scan2 <<<1, 128, 0, stream>>>(part);
  k_scan3 <<<(NN + B-1)/B, B, 0, stream>>>(off, part);
  k_fill  <<<(NE + B-1)/B, B, 0, stream>>>(src, dstp, off, cur, csr);
  k_dinv  <<<(NN + B-1)/B, B, 0, stream>>>(cnt, dinv);

  // GCN
  k_gemm_in   <<<2048, B, 0, stream>>>(x, gcn_w, P_h);
  k_gcn_gather<<<(NN + 3)/4, B, 0, stream>>>(csr, off, P_h, dinv, gcn_b, P_h1);

  // GAT
  k_gat_lin   <<<2048, B, 0, stream>>>(P_h1, gat_w, att_s, att_d, P_h2pre, as_, ad_);
  k_gat_gather<<<(NN + 3)/4, B, 0, stream>>>(csr, off, as_, ad_, P_h2pre, gat_b, P_h2);

  // SAGE (gather + final GEMM fused)
  k_sage_fin  <<<1024, B, 0, stream>>>(csr, off, cnt, P_h2, s_wl, s_wr, s_b, outp);
}